// Round 16
// baseline (1066.258 us; speedup 1.0000x reference)
//
#include <hip/hip_runtime.h>
#include <hip/hip_fp16.h>
#include <math.h>

#define N_AGENT 60000
#define N_MAP   40000
#define N_NODES 100000
#define NE      3200000
#define HID     32
#define PERIODS 30

#define NBUCK   391        // ceil(100000/256) buckets of 256 dst nodes
#define NABUCK  235        // buckets containing agent dsts
#define CAP     10240      // per-bucket capacity (mean 8192, +22 sigma)
#define TILE    4096       // edges per partition block
#define PTHREADS 512
#define ABLK    128        // dsts per k_aggmlp block (one 8-lane group per dst)

// phase-shared LDS buffer (floats). Phase A: edge indices (int). Phase B: weights.
#define BUFSZ   10724
#define OF_MZ   0
#define OF_MH   1024
#define OF_W1   2048
#define OF_W2   4096
#define OF_BZ   10496
#define OF_BH   10528
#define OF_B1   10560
#define OF_B2   10624

// ---------------- kernel 0: fold weights, softmax sum, cursor init ----------------
__global__ void k_precompute(const float* Wz_c, const float* bz_c,
                             const float* Wh_c, const float* bh_c,
                             const float* Wz_l, const float* bz_l,
                             const float* Wh_l, const float* bh_l,
                             const float* attn,
                             float* Mz, float* Mh, float* bz_eff, float* bh_eff,
                             float* s_out, int* cursor) {
    int t = threadIdx.x;            // blockDim = 1024
    int k = t >> 5, c = t & 31;
    float mz = 0.f, mh = 0.f;
    for (int j = 0; j < HID; ++j) {
        mz += Wz_c[k * HID + j] * Wz_l[j * HID + c];   // Wz_l rows 0..31 (zeros half dead)
        mh += Wh_c[k * HID + j] * Wh_l[j * HID + c];
    }
    Mz[t] = mz; Mh[t] = mh;
    if (t < NBUCK) cursor[t] = t * CAP;
    if (t < HID) {
        float bz = bz_l[t], bh = bh_l[t];
        for (int j = 0; j < HID; ++j) {
            bz += bz_c[j] * Wz_l[j * HID + t];
            bh += bh_c[j] * Wh_l[j * HID + t];
        }
        bz_eff[t] = bz; bh_eff[t] = bh;
    }
    if (t == 0) {
        float m = -1e30f;
        for (int i = 0; i < PERIODS; ++i) m = fmaxf(m, attn[i]);
        float S = 0.f;
        for (int i = 0; i < PERIODS; ++i) S += expf(attn[i] - m);
        float s = 0.f;
        for (int i = 0; i < PERIODS; ++i) s += expf(attn[i] - m) / S;
        *s_out = s;
    }
}

// ---------------- kernel 1: LDS-staged multisplit partition (all edges) ----------------
// pack = src | (dst_low << 17); bucket = dst >> 8
// one-pass rank: first LDS atomic returns the local rank; int4-vectorized edge loads.
__global__ __launch_bounds__(PTHREADS) void k_partition(
        const int* __restrict__ src, const int* __restrict__ dst,
        int* __restrict__ cursor, int* __restrict__ ebuf) {
    __shared__ int sCnt[NBUCK];
    __shared__ int sBase[NBUCK + 1];
    __shared__ int sGbase[NBUCK];
    __shared__ int sScan[PTHREADS];
    __shared__ int sReorder[TILE];
    int t = threadIdx.x;
    int tileBase = blockIdx.x * TILE;
    int tcount = NE - tileBase; if (tcount > TILE) tcount = TILE;

    if (t < NBUCK) sCnt[t] = 0;
    __syncthreads();

    int pb[8], pp[8], pr[8];
    const int4* s4 = (const int4*)src;
    const int4* d4 = (const int4*)dst;
#pragma unroll
    for (int k = 0; k < 2; ++k) {
        int e4 = (tileBase >> 2) + t + k * PTHREADS;
        int valid = (e4 << 2) < NE;
        int4 sv, dv;
        if (valid) { sv = s4[e4]; dv = d4[e4]; }
#define PROC(m, SS, DD) { int kk = k * 4 + m;                                  \
        if (valid) { pb[kk] = (DD) >> 8;                                       \
                     pp[kk] = (SS) | (((DD) & 255) << 17);                     \
                     pr[kk] = atomicAdd(&sCnt[pb[kk]], 1); }                   \
        else pb[kk] = -1; }
        PROC(0, sv.x, dv.x)
        PROC(1, sv.y, dv.y)
        PROC(2, sv.z, dv.z)
        PROC(3, sv.w, dv.w)
#undef PROC
    }
    __syncthreads();

    // inclusive scan of sCnt via sScan (Hillis-Steele over 512 threads)
    int v = (t < NBUCK) ? sCnt[t] : 0;
    sScan[t] = v;
    __syncthreads();
    for (int s = 1; s < PTHREADS; s <<= 1) {
        int a = (t >= s) ? sScan[t - s] : 0;
        __syncthreads();
        sScan[t] += a;
        __syncthreads();
    }
    if (t <= NBUCK) sBase[t] = sScan[t] - v;   // exclusive; sBase[NBUCK] = tile total
    __syncthreads();
    // reserve global space
    if (t < NBUCK && sCnt[t] > 0) sGbase[t] = atomicAdd(&cursor[t], sCnt[t]);
    __syncthreads();
    // place by saved rank
#pragma unroll
    for (int k = 0; k < 8; ++k) {
        if (pb[k] >= 0) sReorder[sBase[pb[k]] + pr[k]] = pp[k];
    }
    __syncthreads();
    // coalesced flush: binary-search bucket owning slot j
#pragma unroll
    for (int k = 0; k < 8; ++k) {
        int j = t + k * PTHREADS;
        if (j < tcount) {
            int lo = 0, hi = NBUCK;
            while (hi - lo > 1) {
                int m = (lo + hi) >> 1;
                if (sBase[m] <= j) lo = m; else hi = m;
            }
            ebuf[sGbase[lo] + (j - sBase[lo])] = sReorder[j];
        }
    }
}

// ---------------- kernel 2: per-bucket (dst_low x src-quartile) histogram ----------------
// 1024 bins: bin = dl*4 + quartile(src). Writes deg (sum over quartiles) and qdeg.
__global__ __launch_bounds__(256) void k_hist(const int* __restrict__ cursor,
                                              const int* __restrict__ ebuf,
                                              int* __restrict__ deg,
                                              int* __restrict__ qdeg) {
    __shared__ int h[1024];
    int t = threadIdx.x;
    int b = blockIdx.x;
    for (int j = t; j < 1024; j += 256) h[j] = 0;
    __syncthreads();
    int start = b * CAP;
    int cnt = cursor[b] - start;
    for (int j = t; j < cnt; j += 256) {
        int p = ebuf[start + j];
        int dl = (p >> 17) & 255;
        int s = p & 0x1FFFF;
        int qt = (s >= 25000) + (s >= 50000) + (s >= 75000);
        atomicAdd(&h[dl * 4 + qt], 1);
    }
    __syncthreads();
    int node = b * 256 + t;
    if (node < N_NODES)
        deg[node] = h[t * 4] + h[t * 4 + 1] + h[t * 4 + 2] + h[t * 4 + 3];
    for (int j = t; j < 1024; j += 256) {
        int q4 = b * 1024 + j;
        if (q4 < N_NODES * 4) qdeg[q4] = h[j];
    }
}

// ---------------- kernel 3: node encoders -> fp16 y, pre-scaled by dinv; zero row -------
__global__ void k_encode(const float* __restrict__ agent_x, const float* __restrict__ map_x,
                         const float* __restrict__ W_agent, const float* __restrict__ b_agent,
                         const float* __restrict__ W_map, const float* __restrict__ b_map,
                         const int* __restrict__ deg,
                         __half* __restrict__ y_h) {
    int t = blockIdx.x * blockDim.x + threadIdx.x;
    if (t >= (N_NODES + 1) * HID) return;
    int i = t >> 5, c = t & 31;
    float acc = 0.f;
    if (i < N_AGENT) {
        float v = (c < 9) ? agent_x[(size_t)i * 9 + c] : 0.f;
        acc = b_agent[c];
#pragma unroll
        for (int k = 0; k < 9; ++k) acc += __shfl(v, k, 32) * W_agent[k * HID + c];
        acc *= rsqrtf((float)deg[i] + 1.0f);
    } else if (i < N_NODES) {
        float v = (c < 6) ? map_x[(size_t)(i - N_AGENT) * 6 + c] : 0.f;
        acc = b_map[c];
#pragma unroll
        for (int k = 0; k < 6; ++k) acc += __shfl(v, k, 32) * W_map[k * HID + c];
        acc *= rsqrtf((float)deg[i] + 1.0f);
    }
    y_h[t] = __float2half(acc);       // i == N_NODES -> zero row (gather sink)
}

// ---------------- kernel 4: per-bucket in-place CSR sort, quartile-major within dst -----
__global__ __launch_bounds__(1024) void k_sortlocal(
        const int* __restrict__ cursor, int* __restrict__ ebuf,
        const int* __restrict__ qdeg, int* __restrict__ row_start) {
    __shared__ int sSorted[CAP];          // 40 KB
    __shared__ int sBase[1024];
    __shared__ int sCnt[1024];
    __shared__ int sScan[1024];
    int t = threadIdx.x;
    const int b = blockIdx.x;

    int v = qdeg[b * 1024 + t];
    sCnt[t] = 0;
    sScan[t] = v;
    __syncthreads();
    for (int st = 1; st < 1024; st <<= 1) {
        int a = (t >= st) ? sScan[t - st] : 0;
        __syncthreads();
        sScan[t] += a;
        __syncthreads();
    }
    sBase[t] = sScan[t] - v;              // exclusive over 1024 bins
    if ((t & 3) == 0) row_start[b * 256 + (t >> 2)] = b * CAP + sBase[t];
    __syncthreads();

    const int start = b * CAP;
    const int cnt = cursor[b] - start;
    for (int j = t; j < cnt; j += 1024) {
        int p = ebuf[start + j];
        int dl = (p >> 17) & 255;
        int s = p & 0x1FFFF;
        int qt = (s >= 25000) + (s >= 50000) + (s >= 75000);
        int bin = dl * 4 + qt;
        int r = atomicAdd(&sCnt[bin], 1);
        sSorted[sBase[bin] + r] = s;
    }
    __syncthreads();
    for (int j = t; j < cnt; j += 1024)
        ebuf[start + j] = sSorted[j];      // in place: block owns this range
}

// ---------------- kernel 5: fused CSR gather (fp16) + gates + MLP ----------------
// Round-9 structure + pair epilogue. __launch_bounds__(1024, 4) -> 128-VGPR budget
// (1 block/CU, 16 waves) so the 2-row epilogue fits WITHOUT scratch spill (round-15
// failure: default 64-VGPR budget spilled ~2.7 GB). Gather 1-vs-2 blocks/CU costs
// only ~3% (round 6 vs 7); epilogue LDS traffic is halved (55 -> 27 KB per row).
__global__ __launch_bounds__(1024, 4) void k_aggmlp(
        const int* __restrict__ row_start, const int* __restrict__ deg,
        const int* __restrict__ ebuf, const __half* __restrict__ y_h,
        const float* __restrict__ Mz, const float* __restrict__ Mh,
        const float* __restrict__ bz_eff, const float* __restrict__ bh_eff,
        const float* __restrict__ s_ptr,
        const float* __restrict__ W1, const float* __restrict__ b1,
        const float* __restrict__ W2, const float* __restrict__ b2,
        float* __restrict__ out) {
    __shared__ float sBuf[BUFSZ];         // 42.9 KB, phase-shared
    __shared__ float sAcc[ABLK * 32];     // 16 KB
    __shared__ int   sOff[ABLK + 1];
    int t = threadIdx.x;
    const int nodeBase = blockIdx.x * ABLK;

    if (t < ABLK) sOff[t] = row_start[nodeBase + t];
    if (t == ABLK) {
        int last = nodeBase + ABLK - 1;   // block always inside one bucket (128 | 256)
        sOff[ABLK] = row_start[last] + deg[last];
    }
    __syncthreads();

    // phase A: stage this block's edge indices (cnt <= CAP <= BUFSZ)
    int* sEdge = (int*)sBuf;
    const int e_begin = sOff[0];
    const int cnt = sOff[ABLK] - e_begin;
    for (int j = t; j < cnt; j += 1024) sEdge[j] = ebuf[e_begin + j];
    __syncthreads();

    const int lane = t & 63;
    const int r = (t >> 6) * 8 + (lane >> 3);   // dst row 0..127, one per 8-lane group
    const int q = lane & 7;
    const int i = nodeBase + r;
    const uint2* yh2 = (const uint2*)y_h;       // row i: yh2[i*8 + q] = 4 halves

    if (i < N_AGENT) {
        int e0 = sOff[r] - e_begin, e1 = sOff[r + 1] - e_begin;
        float ax = 0.f, ay = 0.f, az = 0.f, aw = 0.f;
        for (int j = e0; j < e1; j += 8) {
            uint2 v[8];
#pragma unroll
            for (int u = 0; u < 8; ++u) {
                int idx = (j + u < e1) ? sEdge[j + u] : N_NODES;
                v[u] = yh2[(size_t)idx * 8 + q];
            }
#pragma unroll
            for (int u = 0; u < 8; ++u) {
                __half2 h0 = *reinterpret_cast<__half2*>(&v[u].x);
                __half2 h1 = *reinterpret_cast<__half2*>(&v[u].y);
                float2 f0 = __half22float2(h0);
                float2 f1 = __half22float2(h1);
                ax += f0.x; ay += f0.y; az += f1.x; aw += f1.y;
            }
        }
        *(float4*)&sAcc[r * 32 + q * 4] = make_float4(ax, ay, az, aw);
    }
    __syncthreads();

    // phase B: overwrite sBuf with epilogue weights (L2-hot, ~11 loads/thread)
    sBuf[OF_MZ + t] = Mz[t];
    sBuf[OF_MH + t] = Mh[t];
    for (int j = t; j < 2048; j += 1024) sBuf[OF_W1 + j] = W1[j];
    for (int j = t; j < 6400; j += 1024) sBuf[OF_W2 + j] = W2[j];
    if (t < 32) { sBuf[OF_BZ + t] = bz_eff[t]; sBuf[OF_BH + t] = bh_eff[t]; }
    if (t >= 64 && t < 128) sBuf[OF_B1 + t - 64] = b1[t - 64];
    if (t >= 128 && t < 228) sBuf[OF_B2 + t - 128] = b2[t - 128];
    __syncthreads();

    // epilogue: 32 groups of 32 lanes, processing row pairs (rr, rr+64)
    const float s = *s_ptr;
    const int c = t & 31, g2 = t >> 5;
    for (int rr = g2; rr < 64; rr += 32) {
        int iA = nodeBase + rr;          // always < N_AGENT (nodeBase+63 <= 59967)
        int iB = iA + 64;
        bool vB = (iB < N_AGENT);
        float diA = rsqrtf((float)deg[iA] + 1.0f);
        float diB = vB ? rsqrtf((float)deg[iB] + 1.0f) : 0.f;
        float selfA = __half2float(y_h[(size_t)iA * HID + c]);
        float selfB = vB ? __half2float(y_h[(size_t)iB * HID + c]) : 0.f;
        float aA = (sAcc[rr * 32 + c] + selfA) * diA;
        float aB = vB ? (sAcc[(rr + 64) * 32 + c] + selfB) * diB : 0.f;

        float uzA = sBuf[OF_BZ + c], uhA = sBuf[OF_BH + c];
        float uzB = uzA, uhB = uhA;
#pragma unroll
        for (int k = 0; k < 32; ++k) {
            float mz = sBuf[OF_MZ + k * 32 + c];
            float mh = sBuf[OF_MH + k * 32 + c];
            float akA = __shfl(aA, k, 32);
            float akB = __shfl(aB, k, 32);
            uzA += akA * mz; uhA += akA * mh;
            uzB += akB * mz; uhB += akB * mh;
        }
        float zA = 1.0f / (1.0f + expf(-uzA));
        float hA = fmaxf(s * (1.0f - zA) * tanhf(uhA), 0.0f);
        float zB = 1.0f / (1.0f + expf(-uzB));
        float hB = fmaxf(s * (1.0f - zB) * tanhf(uhB), 0.0f);

        float t0A = sBuf[OF_B1 + c], t1A = sBuf[OF_B1 + c + 32];
        float t0B = t0A, t1B = t1A;
#pragma unroll
        for (int k = 0; k < 32; ++k) {
            float w0 = sBuf[OF_W1 + k * 64 + c];
            float w1 = sBuf[OF_W1 + k * 64 + c + 32];
            float hkA = __shfl(hA, k, 32);
            float hkB = __shfl(hB, k, 32);
            t0A += hkA * w0; t1A += hkA * w1;
            t0B += hkB * w0; t1B += hkB * w1;
        }
        t0A = fmaxf(t0A, 0.f); t1A = fmaxf(t1A, 0.f);
        t0B = fmaxf(t0B, 0.f); t1B = fmaxf(t1B, 0.f);

        int j3 = (c < 4) ? (c + 96) : 99;
        float o0A = sBuf[OF_B2 + c],      o0B = o0A;
        float o1A = sBuf[OF_B2 + c + 32], o1B = o1A;
        float o2A = sBuf[OF_B2 + c + 64], o2B = o2A;
        float o3A = sBuf[OF_B2 + j3],     o3B = o3A;
#pragma unroll
        for (int k = 0; k < 32; ++k) {
            float wa0 = sBuf[OF_W2 + k * 100 + c];
            float wb0 = sBuf[OF_W2 + (k + 32) * 100 + c];
            float wa1 = sBuf[OF_W2 + k * 100 + c + 32];
            float wb1 = sBuf[OF_W2 + (k + 32) * 100 + c + 32];
            float wa2 = sBuf[OF_W2 + k * 100 + c + 64];
            float wb2 = sBuf[OF_W2 + (k + 32) * 100 + c + 64];
            float wa3 = sBuf[OF_W2 + k * 100 + j3];
            float wb3 = sBuf[OF_W2 + (k + 32) * 100 + j3];
            float taA = __shfl(t0A, k, 32), tbA = __shfl(t1A, k, 32);
            float taB = __shfl(t0B, k, 32), tbB = __shfl(t1B, k, 32);
            o0A += taA * wa0 + tbA * wb0;  o0B += taB * wa0 + tbB * wb0;
            o1A += taA * wa1 + tbA * wb1;  o1B += taB * wa1 + tbB * wb1;
            o2A += taA * wa2 + tbA * wb2;  o2B += taB * wa2 + tbB * wb2;
            o3A += taA * wa3 + tbA * wb3;  o3B += taB * wa3 + tbB * wb3;
        }
        float* orowA = out + (size_t)iA * 100;
        orowA[c] = o0A;
        orowA[c + 32] = o1A;
        orowA[c + 64] = o2A;
        if (c < 4) orowA[c + 96] = o3A;
        if (vB) {
            float* orowB = out + (size_t)iB * 100;
            orowB[c] = o0B;
            orowB[c + 32] = o1B;
            orowB[c + 64] = o2B;
            if (c < 4) orowB[c + 96] = o3B;
        }
    }
}

extern "C" void kernel_launch(void* const* d_in, const int* in_sizes, int n_in,
                              void* d_out, int out_size, void* d_ws, size_t ws_size,
                              hipStream_t stream) {
    const float* agent_x = (const float*)d_in[0];
    const float* map_x   = (const float*)d_in[1];
    const int*   ei      = (const int*)d_in[2];
    const float* W_agent = (const float*)d_in[3];
    const float* b_agent = (const float*)d_in[4];
    const float* W_map   = (const float*)d_in[5];
    const float* b_map   = (const float*)d_in[6];
    const float* Wz_c    = (const float*)d_in[7];
    const float* bz_c    = (const float*)d_in[8];
    const float* Wh_c    = (const float*)d_in[11];
    const float* bh_c    = (const float*)d_in[12];
    const float* Wz_l    = (const float*)d_in[13];
    const float* bz_l    = (const float*)d_in[14];
    const float* Wh_l    = (const float*)d_in[17];
    const float* bh_l    = (const float*)d_in[18];
    const float* attn    = (const float*)d_in[19];
    const float* W1      = (const float*)d_in[20];
    const float* b1      = (const float*)d_in[21];
    const float* W2      = (const float*)d_in[22];
    const float* b2      = (const float*)d_in[23];
    float* out = (float*)d_out;

    const int* e_src = ei;
    const int* e_dst = ei + NE;

    // workspace layout (float-element offsets); total ~24.7 MB
    float*  ws       = (float*)d_ws;
    __half* y_h      = (__half*)ws;                 // (N_NODES+1)*32 halves (pad to 1,600,128 floats)
    float*  Mz       = ws + 1600128;                // 1024
    float*  Mh       = ws + 1601152;                // 1024
    float*  bz       = ws + 1602176;                // 32
    float*  bh       = ws + 1602208;                // 32
    float*  sS       = ws + 1602240;                // 1 (pad to 1602304)
    int*    deg      = (int*)(ws + 1602304);        // 100,000 (pad to 1702400)
    int*    cursor   = (int*)(ws + 1702400);        // 391 (pad to 1702912)
    int*    row_start= (int*)(ws + 1702912);        // 60,160 (pad to 1763328)
    int*    qdeg     = (int*)(ws + 1763328);        // 400,000 -> 2163328
    int*    ebuf     = (int*)(ws + 2163328);        // NBUCK*CAP = 4,003,840 -> end 6,167,168

    k_precompute<<<1, 1024, 0, stream>>>(Wz_c, bz_c, Wh_c, bh_c, Wz_l, bz_l,
                                         Wh_l, bh_l, attn, Mz, Mh, bz, bh, sS, cursor);
    k_partition<<<(NE + TILE - 1) / TILE, PTHREADS, 0, stream>>>(e_src, e_dst, cursor, ebuf);
    k_hist<<<NBUCK, 256, 0, stream>>>(cursor, ebuf, deg, qdeg);
    k_encode<<<((N_NODES + 1) * HID + 255) / 256, 256, 0, stream>>>(
        agent_x, map_x, W_agent, b_agent, W_map, b_map, deg, y_h);
    k_sortlocal<<<NABUCK, 1024, 0, stream>>>(cursor, ebuf, qdeg, row_start);
    k_aggmlp<<<(N_AGENT + ABLK - 1) / ABLK, 1024, 0, stream>>>(
        row_start, deg, ebuf, y_h, Mz, Mh, bz, bh, sS, W1, b1, W2, b2, out);
}

// Round 17
// 303.448 us; speedup vs baseline: 3.5138x; 3.5138x over previous
//
#include <hip/hip_runtime.h>
#include <hip/hip_fp16.h>
#include <math.h>

#define N_AGENT 60000
#define N_MAP   40000
#define N_NODES 100000
#define NE      3200000
#define HID     32
#define PERIODS 30

#define NBUCK   391        // ceil(100000/256) buckets of 256 dst nodes
#define NABUCK  235        // buckets containing agent dsts
#define CAP     10240      // per-bucket capacity (mean 8192, +22 sigma)
#define TILE    4096       // edges per partition block
#define PTHREADS 512
#define ABLK    128        // dsts per k_aggmlp block (one 8-lane group per dst)

// phase-shared LDS buffer (floats). Phase A: edge indices (int). Phase B: weights.
#define BUFSZ   10724
#define OF_MZ   0
#define OF_MH   1024
#define OF_W1   2048
#define OF_W2   4096
#define OF_BZ   10496
#define OF_BH   10528
#define OF_B1   10560
#define OF_B2   10624

// ---------------- kernel 0: fold weights, softmax sum, cursor init ----------------
__global__ void k_precompute(const float* Wz_c, const float* bz_c,
                             const float* Wh_c, const float* bh_c,
                             const float* Wz_l, const float* bz_l,
                             const float* Wh_l, const float* bh_l,
                             const float* attn,
                             float* Mz, float* Mh, float* bz_eff, float* bh_eff,
                             float* s_out, int* cursor) {
    int t = threadIdx.x;            // blockDim = 1024
    int k = t >> 5, c = t & 31;
    float mz = 0.f, mh = 0.f;
    for (int j = 0; j < HID; ++j) {
        mz += Wz_c[k * HID + j] * Wz_l[j * HID + c];   // Wz_l rows 0..31 (zeros half dead)
        mh += Wh_c[k * HID + j] * Wh_l[j * HID + c];
    }
    Mz[t] = mz; Mh[t] = mh;
    if (t < NBUCK) cursor[t] = t * CAP;
    if (t < HID) {
        float bz = bz_l[t], bh = bh_l[t];
        for (int j = 0; j < HID; ++j) {
            bz += bz_c[j] * Wz_l[j * HID + t];
            bh += bh_c[j] * Wh_l[j * HID + t];
        }
        bz_eff[t] = bz; bh_eff[t] = bh;
    }
    if (t == 0) {
        float m = -1e30f;
        for (int i = 0; i < PERIODS; ++i) m = fmaxf(m, attn[i]);
        float S = 0.f;
        for (int i = 0; i < PERIODS; ++i) S += expf(attn[i] - m);
        float s = 0.f;
        for (int i = 0; i < PERIODS; ++i) s += expf(attn[i] - m) / S;
        *s_out = s;
    }
}

// ---------------- kernel 1: LDS-staged multisplit partition (all edges) ----------------
// pack = src | (dst_low << 17); bucket = dst >> 8
// one-pass rank (first LDS atomic returns rank); int4 edge loads.
// Flush uses a slot->bucket TABLE (sBkt, recorded at placement) instead of the
// 9-deep binary search: 72 dependent LDS reads/thread -> 2 independent reads.
__global__ __launch_bounds__(PTHREADS) void k_partition(
        const int* __restrict__ src, const int* __restrict__ dst,
        int* __restrict__ cursor, int* __restrict__ ebuf) {
    __shared__ int sCnt[NBUCK];
    __shared__ int sBase[NBUCK + 1];
    __shared__ int sGbase[NBUCK];
    __shared__ int sScan[PTHREADS];
    __shared__ int sReorder[TILE];
    __shared__ unsigned short sBkt[TILE];
    int t = threadIdx.x;
    int tileBase = blockIdx.x * TILE;
    int tcount = NE - tileBase; if (tcount > TILE) tcount = TILE;

    if (t < NBUCK) sCnt[t] = 0;
    __syncthreads();

    int pb[8], pp[8], pr[8];
    const int4* s4 = (const int4*)src;
    const int4* d4 = (const int4*)dst;
#pragma unroll
    for (int k = 0; k < 2; ++k) {
        int e4 = (tileBase >> 2) + t + k * PTHREADS;
        int valid = (e4 << 2) < NE;
        int4 sv, dv;
        if (valid) { sv = s4[e4]; dv = d4[e4]; }
#define PROC(m, SS, DD) { int kk = k * 4 + m;                                  \
        if (valid) { pb[kk] = (DD) >> 8;                                       \
                     pp[kk] = (SS) | (((DD) & 255) << 17);                     \
                     pr[kk] = atomicAdd(&sCnt[pb[kk]], 1); }                   \
        else pb[kk] = -1; }
        PROC(0, sv.x, dv.x)
        PROC(1, sv.y, dv.y)
        PROC(2, sv.z, dv.z)
        PROC(3, sv.w, dv.w)
#undef PROC
    }
    __syncthreads();

    // inclusive scan of sCnt via sScan (Hillis-Steele over 512 threads)
    int v = (t < NBUCK) ? sCnt[t] : 0;
    sScan[t] = v;
    __syncthreads();
    for (int s = 1; s < PTHREADS; s <<= 1) {
        int a = (t >= s) ? sScan[t - s] : 0;
        __syncthreads();
        sScan[t] += a;
        __syncthreads();
    }
    if (t <= NBUCK) sBase[t] = sScan[t] - v;   // exclusive; sBase[NBUCK] = tile total
    __syncthreads();
    // reserve global space
    if (t < NBUCK && sCnt[t] > 0) sGbase[t] = atomicAdd(&cursor[t], sCnt[t]);
    __syncthreads();
    // place by saved rank + record slot's bucket
#pragma unroll
    for (int k = 0; k < 8; ++k) {
        if (pb[k] >= 0) {
            int slot = sBase[pb[k]] + pr[k];
            sReorder[slot] = pp[k];
            sBkt[slot] = (unsigned short)pb[k];
        }
    }
    __syncthreads();
    // coalesced flush: bucket from table (no search)
#pragma unroll
    for (int k = 0; k < 8; ++k) {
        int j = t + k * PTHREADS;
        if (j < tcount) {
            int lo = sBkt[j];
            ebuf[sGbase[lo] + (j - sBase[lo])] = sReorder[j];
        }
    }
}

// ---------------- kernel 2: per-bucket (dst_low x src-quartile) histogram ----------------
// 1024 bins: bin = dl*4 + quartile(src). Writes deg (sum over quartiles) and qdeg.
__global__ __launch_bounds__(256) void k_hist(const int* __restrict__ cursor,
                                              const int* __restrict__ ebuf,
                                              int* __restrict__ deg,
                                              int* __restrict__ qdeg) {
    __shared__ int h[1024];
    int t = threadIdx.x;
    int b = blockIdx.x;
    for (int j = t; j < 1024; j += 256) h[j] = 0;
    __syncthreads();
    int start = b * CAP;
    int cnt = cursor[b] - start;
    for (int j = t; j < cnt; j += 256) {
        int p = ebuf[start + j];
        int dl = (p >> 17) & 255;
        int s = p & 0x1FFFF;
        int qt = (s >= 25000) + (s >= 50000) + (s >= 75000);
        atomicAdd(&h[dl * 4 + qt], 1);
    }
    __syncthreads();
    int node = b * 256 + t;
    if (node < N_NODES)
        deg[node] = h[t * 4] + h[t * 4 + 1] + h[t * 4 + 2] + h[t * 4 + 3];
    for (int j = t; j < 1024; j += 256) {
        int q4 = b * 1024 + j;
        if (q4 < N_NODES * 4) qdeg[q4] = h[j];
    }
}

// ---------------- kernel 3: node encoders -> fp16 y, pre-scaled by dinv; zero row -------
__global__ void k_encode(const float* __restrict__ agent_x, const float* __restrict__ map_x,
                         const float* __restrict__ W_agent, const float* __restrict__ b_agent,
                         const float* __restrict__ W_map, const float* __restrict__ b_map,
                         const int* __restrict__ deg,
                         __half* __restrict__ y_h) {
    int t = blockIdx.x * blockDim.x + threadIdx.x;
    if (t >= (N_NODES + 1) * HID) return;
    int i = t >> 5, c = t & 31;
    float acc = 0.f;
    if (i < N_AGENT) {
        float v = (c < 9) ? agent_x[(size_t)i * 9 + c] : 0.f;
        acc = b_agent[c];
#pragma unroll
        for (int k = 0; k < 9; ++k) acc += __shfl(v, k, 32) * W_agent[k * HID + c];
        acc *= rsqrtf((float)deg[i] + 1.0f);
    } else if (i < N_NODES) {
        float v = (c < 6) ? map_x[(size_t)(i - N_AGENT) * 6 + c] : 0.f;
        acc = b_map[c];
#pragma unroll
        for (int k = 0; k < 6; ++k) acc += __shfl(v, k, 32) * W_map[k * HID + c];
        acc *= rsqrtf((float)deg[i] + 1.0f);
    }
    y_h[t] = __float2half(acc);       // i == N_NODES -> zero row (gather sink)
}

// ---------------- kernel 4: per-bucket in-place CSR sort, quartile-major within dst -----
__global__ __launch_bounds__(1024) void k_sortlocal(
        const int* __restrict__ cursor, int* __restrict__ ebuf,
        const int* __restrict__ qdeg, int* __restrict__ row_start) {
    __shared__ int sSorted[CAP];          // 40 KB
    __shared__ int sBase[1024];
    __shared__ int sCnt[1024];
    __shared__ int sScan[1024];
    int t = threadIdx.x;
    const int b = blockIdx.x;

    int v = qdeg[b * 1024 + t];
    sCnt[t] = 0;
    sScan[t] = v;
    __syncthreads();
    for (int st = 1; st < 1024; st <<= 1) {
        int a = (t >= st) ? sScan[t - st] : 0;
        __syncthreads();
        sScan[t] += a;
        __syncthreads();
    }
    sBase[t] = sScan[t] - v;              // exclusive over 1024 bins
    if ((t & 3) == 0) row_start[b * 256 + (t >> 2)] = b * CAP + sBase[t];
    __syncthreads();

    const int start = b * CAP;
    const int cnt = cursor[b] - start;
    for (int j = t; j < cnt; j += 1024) {
        int p = ebuf[start + j];
        int dl = (p >> 17) & 255;
        int s = p & 0x1FFFF;
        int qt = (s >= 25000) + (s >= 50000) + (s >= 75000);
        int bin = dl * 4 + qt;
        int r = atomicAdd(&sCnt[bin], 1);
        sSorted[sBase[bin] + r] = s;
    }
    __syncthreads();
    for (int j = t; j < cnt; j += 1024)
        ebuf[start + j] = sSorted[j];      // in place: block owns this range
}

// ---------------- kernel 5: fused CSR gather (fp16) + gates + MLP ----------------
// Round-9 verified structure: one 8-lane group per dst; 8-edge predicated unroll;
// phase-shared LDS (edges then weights); single-row epilogue (no spill, VGPR 64).
__global__ __launch_bounds__(1024) void k_aggmlp(
        const int* __restrict__ row_start, const int* __restrict__ deg,
        const int* __restrict__ ebuf, const __half* __restrict__ y_h,
        const float* __restrict__ Mz, const float* __restrict__ Mh,
        const float* __restrict__ bz_eff, const float* __restrict__ bh_eff,
        const float* __restrict__ s_ptr,
        const float* __restrict__ W1, const float* __restrict__ b1,
        const float* __restrict__ W2, const float* __restrict__ b2,
        float* __restrict__ out) {
    __shared__ float sBuf[BUFSZ];         // 42.9 KB, phase-shared
    __shared__ float sAcc[ABLK * 32];     // 16 KB
    __shared__ int   sOff[ABLK + 1];
    int t = threadIdx.x;
    const int nodeBase = blockIdx.x * ABLK;

    if (t < ABLK) sOff[t] = row_start[nodeBase + t];
    if (t == ABLK) {
        int last = nodeBase + ABLK - 1;   // block always inside one bucket (128 | 256)
        sOff[ABLK] = row_start[last] + deg[last];
    }
    __syncthreads();

    // phase A: stage this block's edge indices (cnt <= CAP <= BUFSZ)
    int* sEdge = (int*)sBuf;
    const int e_begin = sOff[0];
    const int cnt = sOff[ABLK] - e_begin;
    for (int j = t; j < cnt; j += 1024) sEdge[j] = ebuf[e_begin + j];
    __syncthreads();

    const int lane = t & 63;
    const int r = (t >> 6) * 8 + (lane >> 3);   // dst row 0..127, one per 8-lane group
    const int q = lane & 7;
    const int i = nodeBase + r;
    const uint2* yh2 = (const uint2*)y_h;       // row i: yh2[i*8 + q] = 4 halves

    if (i < N_AGENT) {
        int e0 = sOff[r] - e_begin, e1 = sOff[r + 1] - e_begin;
        float ax = 0.f, ay = 0.f, az = 0.f, aw = 0.f;
        for (int j = e0; j < e1; j += 8) {
            uint2 v[8];
#pragma unroll
            for (int u = 0; u < 8; ++u) {
                int idx = (j + u < e1) ? sEdge[j + u] : N_NODES;
                v[u] = yh2[(size_t)idx * 8 + q];
            }
#pragma unroll
            for (int u = 0; u < 8; ++u) {
                __half2 h0 = *reinterpret_cast<__half2*>(&v[u].x);
                __half2 h1 = *reinterpret_cast<__half2*>(&v[u].y);
                float2 f0 = __half22float2(h0);
                float2 f1 = __half22float2(h1);
                ax += f0.x; ay += f0.y; az += f1.x; aw += f1.y;
            }
        }
        *(float4*)&sAcc[r * 32 + q * 4] = make_float4(ax, ay, az, aw);
    }
    __syncthreads();

    // phase B: overwrite sBuf with epilogue weights (L2-hot, ~11 loads/thread)
    sBuf[OF_MZ + t] = Mz[t];
    sBuf[OF_MH + t] = Mh[t];
    for (int j = t; j < 2048; j += 1024) sBuf[OF_W1 + j] = W1[j];
    for (int j = t; j < 6400; j += 1024) sBuf[OF_W2 + j] = W2[j];
    if (t < 32) { sBuf[OF_BZ + t] = bz_eff[t]; sBuf[OF_BH + t] = bh_eff[t]; }
    if (t >= 64 && t < 128) sBuf[OF_B1 + t - 64] = b1[t - 64];
    if (t >= 128 && t < 228) sBuf[OF_B2 + t - 128] = b2[t - 128];
    __syncthreads();

    // epilogue: 32 groups of 32 lanes, 4 rows each
    const float s = *s_ptr;
    const int c = t & 31, g2 = t >> 5;
    for (int rr = g2; rr < ABLK; rr += 32) {
        int ii = nodeBase + rr;
        if (ii >= N_AGENT) break;
        float di = rsqrtf((float)deg[ii] + 1.0f);
        float selfv = __half2float(y_h[(size_t)ii * HID + c]);
        float a = (sAcc[rr * 32 + c] + selfv) * di;
        float uz = sBuf[OF_BZ + c], uh = sBuf[OF_BH + c];
#pragma unroll
        for (int k = 0; k < 32; ++k) {
            float ak = __shfl(a, k, 32);
            uz += ak * sBuf[OF_MZ + k * 32 + c];
            uh += ak * sBuf[OF_MH + k * 32 + c];
        }
        float z = 1.0f / (1.0f + expf(-uz));
        float h = s * (1.0f - z) * tanhf(uh);
        h = fmaxf(h, 0.0f);
        float t0 = sBuf[OF_B1 + c], t1 = sBuf[OF_B1 + c + 32];
#pragma unroll
        for (int k = 0; k < 32; ++k) {
            float hk = __shfl(h, k, 32);
            t0 += hk * sBuf[OF_W1 + k * 64 + c];
            t1 += hk * sBuf[OF_W1 + k * 64 + c + 32];
        }
        t0 = fmaxf(t0, 0.0f); t1 = fmaxf(t1, 0.0f);
        int j3 = (c < 4) ? (c + 96) : 99;
        float o0 = sBuf[OF_B2 + c];
        float o1 = sBuf[OF_B2 + c + 32];
        float o2 = sBuf[OF_B2 + c + 64];
        float o3 = sBuf[OF_B2 + j3];
#pragma unroll
        for (int k = 0; k < 32; ++k) {
            float ta = __shfl(t0, k, 32);
            float tb = __shfl(t1, k, 32);
            o0 += ta * sBuf[OF_W2 + k * 100 + c]      + tb * sBuf[OF_W2 + (k + 32) * 100 + c];
            o1 += ta * sBuf[OF_W2 + k * 100 + c + 32] + tb * sBuf[OF_W2 + (k + 32) * 100 + c + 32];
            o2 += ta * sBuf[OF_W2 + k * 100 + c + 64] + tb * sBuf[OF_W2 + (k + 32) * 100 + c + 64];
            o3 += ta * sBuf[OF_W2 + k * 100 + j3]     + tb * sBuf[OF_W2 + (k + 32) * 100 + j3];
        }
        float* orow = out + (size_t)ii * 100;
        orow[c] = o0;
        orow[c + 32] = o1;
        orow[c + 64] = o2;
        if (c < 4) orow[c + 96] = o3;
    }
}

extern "C" void kernel_launch(void* const* d_in, const int* in_sizes, int n_in,
                              void* d_out, int out_size, void* d_ws, size_t ws_size,
                              hipStream_t stream) {
    const float* agent_x = (const float*)d_in[0];
    const float* map_x   = (const float*)d_in[1];
    const int*   ei      = (const int*)d_in[2];
    const float* W_agent = (const float*)d_in[3];
    const float* b_agent = (const float*)d_in[4];
    const float* W_map   = (const float*)d_in[5];
    const float* b_map   = (const float*)d_in[6];
    const float* Wz_c    = (const float*)d_in[7];
    const float* bz_c    = (const float*)d_in[8];
    const float* Wh_c    = (const float*)d_in[11];
    const float* bh_c    = (const float*)d_in[12];
    const float* Wz_l    = (const float*)d_in[13];
    const float* bz_l    = (const float*)d_in[14];
    const float* Wh_l    = (const float*)d_in[17];
    const float* bh_l    = (const float*)d_in[18];
    const float* attn    = (const float*)d_in[19];
    const float* W1      = (const float*)d_in[20];
    const float* b1      = (const float*)d_in[21];
    const float* W2      = (const float*)d_in[22];
    const float* b2      = (const float*)d_in[23];
    float* out = (float*)d_out;

    const int* e_src = ei;
    const int* e_dst = ei + NE;

    // workspace layout (float-element offsets); total ~24.7 MB
    float*  ws       = (float*)d_ws;
    __half* y_h      = (__half*)ws;                 // (N_NODES+1)*32 halves (pad to 1,600,128 floats)
    float*  Mz       = ws + 1600128;                // 1024
    float*  Mh       = ws + 1601152;                // 1024
    float*  bz       = ws + 1602176;                // 32
    float*  bh       = ws + 1602208;                // 32
    float*  sS       = ws + 1602240;                // 1 (pad to 1602304)
    int*    deg      = (int*)(ws + 1602304);        // 100,000 (pad to 1702400)
    int*    cursor   = (int*)(ws + 1702400);        // 391 (pad to 1702912)
    int*    row_start= (int*)(ws + 1702912);        // 60,160 (pad to 1763328)
    int*    qdeg     = (int*)(ws + 1763328);        // 400,000 -> 2163328
    int*    ebuf     = (int*)(ws + 2163328);        // NBUCK*CAP = 4,003,840 -> end 6,167,168

    k_precompute<<<1, 1024, 0, stream>>>(Wz_c, bz_c, Wh_c, bh_c, Wz_l, bz_l,
                                         Wh_l, bh_l, attn, Mz, Mh, bz, bh, sS, cursor);
    k_partition<<<(NE + TILE - 1) / TILE, PTHREADS, 0, stream>>>(e_src, e_dst, cursor, ebuf);
    k_hist<<<NBUCK, 256, 0, stream>>>(cursor, ebuf, deg, qdeg);
    k_encode<<<((N_NODES + 1) * HID + 255) / 256, 256, 0, stream>>>(
        agent_x, map_x, W_agent, b_agent, W_map, b_map, deg, y_h);
    k_sortlocal<<<NABUCK, 1024, 0, stream>>>(cursor, ebuf, qdeg, row_start);
    k_aggmlp<<<(N_AGENT + ABLK - 1) / ABLK, 1024, 0, stream>>>(
        row_start, deg, ebuf, y_h, Mz, Mh, bz, bh, sS, W1, b1, W2, b2, out);
}